// Round 8
// baseline (900.090 us; speedup 1.0000x reference)
//
#include <hip/hip_runtime.h>
#include <hip/hip_bf16.h>

// KGAT, bucket-aggregated (bucket = 128 heads, NBK = ceil(N/128) = 1563):
//   k1 hdot:   hdot[n] = emb[n].att_w[0:64];  rb[r] = rel[r].att_w[64:128] + b
//   k2 bhist:  per-block LDS histogram of head>>7, batched flush to padded bcnt
//   k3 bscan:  1-block exclusive scan of 1563 bucket counts -> boff, gcur
//   k4 scatter1: per-block chunk (6144 edges): LDS hist -> LDS scan -> LDS group
//              -> burst copy-out at atomically-reserved global base (coalesced
//              runs; kills the 16x partial-line write amplification)
//              packed 4B: (head&127)<<19 | rel<<18 | tail(18b)
//   k5 aggr_fused: block per bucket; acc[128][64] in LDS via f32 LDS atomics;
//              then tanh(acc @ W^T + b) from LDS (16-lane/row shfl scheme).

#define DIM 64
#define TMASK 0x3FFFF
#define RBIT (1 << 18)
#define BSH 7            // 128 heads per bucket
#define NBK_MAX 1600     // >= ceil(200000/128) = 1563
#define CHUNK 6144
#define SCAN_ITEMS 7     // 256*7 = 1792 >= NBK

// ---------------- k1: per-entity attention dot ----------------
__global__ __launch_bounds__(256) void kgat_hdot(
    const float* __restrict__ emb, const float* __restrict__ rel,
    const float* __restrict__ att_w, const float* __restrict__ att_b,
    float* __restrict__ hdot, float* __restrict__ rb,
    int n_ent, int n_rel) {
  int gid = blockIdx.x * 256 + threadIdx.x;
  int n = gid >> 4;
  int q = threadIdx.x & 15;
  if (n >= n_ent + n_rel) return;
  float4 v, w;
  if (n < n_ent) {
    v = ((const float4*)emb)[n * 16 + q];
    w = ((const float4*)att_w)[q];
  } else {
    v = ((const float4*)rel)[(n - n_ent) * 16 + q];
    w = ((const float4*)att_w)[16 + q];
  }
  float p = v.x * w.x + v.y * w.y + v.z * w.z + v.w * w.w;
  p += __shfl_xor(p, 1);
  p += __shfl_xor(p, 2);
  p += __shfl_xor(p, 4);
  p += __shfl_xor(p, 8);
  if (q == 0) {
    if (n < n_ent) hdot[n] = p;
    else rb[n - n_ent] = p + att_b[0];
  }
}

// ---------------- k2: bucket histogram (LDS, batched flush) ----------------
__global__ __launch_bounds__(256) void kgat_bhist(
    const int* __restrict__ ei, int* __restrict__ bcnt, int E, int nbk) {
  __shared__ int hist[NBK_MAX];
  for (int i = threadIdx.x; i < NBK_MAX; i += 256) hist[i] = 0;
  __syncthreads();
  int base = blockIdx.x * CHUNK;
  for (int i = threadIdx.x; i < CHUNK; i += 256) {
    int e = base + i;
    if (e < E) atomicAdd(&hist[ei[e] >> BSH], 1);
  }
  __syncthreads();
  for (int b = threadIdx.x; b < nbk; b += 256) {
    int c = hist[b];
    if (c) atomicAdd(&bcnt[b << 4], c);  // padded: 1 counter / 64B line
  }
}

// ---------------- k3: 1-block scan of bucket counts ----------------
__global__ __launch_bounds__(256) void kgat_bscan(
    const int* __restrict__ bcnt, int* __restrict__ boff,
    int* __restrict__ gcur, int nbk) {
  __shared__ int sblk[256];
  int v[SCAN_ITEMS];
  int s = 0;
#pragma unroll
  for (int k = 0; k < SCAN_ITEMS; ++k) {
    int idx = threadIdx.x * SCAN_ITEMS + k;
    v[k] = (idx < nbk) ? bcnt[idx << 4] : 0;
    s += v[k];
  }
  sblk[threadIdx.x] = s;
  __syncthreads();
  for (int d = 1; d < 256; d <<= 1) {
    int t = (threadIdx.x >= (unsigned)d) ? sblk[threadIdx.x - d] : 0;
    __syncthreads();
    sblk[threadIdx.x] += t;
    __syncthreads();
  }
  int excl = sblk[threadIdx.x] - s;
#pragma unroll
  for (int k = 0; k < SCAN_ITEMS; ++k) {
    int idx = threadIdx.x * SCAN_ITEMS + k;
    if (idx < nbk) {
      boff[idx] = excl;
      gcur[idx << 4] = excl;
    }
    excl += v[k];
  }
  if (threadIdx.x == 255) boff[nbk] = excl;  // = E
}

// ---------------- k4: binned scatter with coalesced burst writes ----------------
__global__ __launch_bounds__(256) void kgat_scatter1(
    const int* __restrict__ ei, const int* __restrict__ et,
    int* __restrict__ gcur, int* __restrict__ stage, int E, int nbk) {
  __shared__ int hist[NBK_MAX];    // counts, then gbase
  __shared__ int lstart[NBK_MAX];
  __shared__ int lcur[NBK_MAX];
  __shared__ int sblk[256];
  __shared__ int vals[CHUNK];
  __shared__ unsigned short bid[CHUNK];
  int base = blockIdx.x * CHUNK;
  // phase 1: zero + local histogram
  for (int i = threadIdx.x; i < NBK_MAX; i += 256) hist[i] = 0;
  __syncthreads();
  for (int i = threadIdx.x; i < CHUNK; i += 256) {
    int e = base + i;
    if (e < E) atomicAdd(&hist[ei[e] >> BSH], 1);
  }
  __syncthreads();
  // phase 2: LDS scan -> lstart/lcur
  int v[SCAN_ITEMS];
  int s = 0;
#pragma unroll
  for (int k = 0; k < SCAN_ITEMS; ++k) {
    int idx = threadIdx.x * SCAN_ITEMS + k;
    v[k] = (idx < nbk) ? hist[idx] : 0;
    s += v[k];
  }
  sblk[threadIdx.x] = s;
  __syncthreads();
  for (int d = 1; d < 256; d <<= 1) {
    int t = (threadIdx.x >= (unsigned)d) ? sblk[threadIdx.x - d] : 0;
    __syncthreads();
    sblk[threadIdx.x] += t;
    __syncthreads();
  }
  int excl = sblk[threadIdx.x] - s;
#pragma unroll
  for (int k = 0; k < SCAN_ITEMS; ++k) {
    int idx = threadIdx.x * SCAN_ITEMS + k;
    if (idx < nbk) {
      lstart[idx] = excl;
      lcur[idx] = excl;
    }
    excl += v[k];
  }
  __syncthreads();
  // phase 3: reserve global ranges (counts still in hist) -> hist := gbase
  for (int b = threadIdx.x; b < nbk; b += 256) {
    int c = hist[b];
    hist[b] = c ? atomicAdd(&gcur[b << 4], c) : 0;
  }
  __syncthreads();
  // phase 4: re-read edges, group into LDS
  for (int i = threadIdx.x; i < CHUNK; i += 256) {
    int e = base + i;
    if (e < E) {
      int h = ei[e];
      int t = ei[E + e];
      int r = et[e];
      int b = h >> BSH;
      int pos = atomicAdd(&lcur[b], 1);
      vals[pos] = t | (r << 18) | ((h & 127) << 19);
      bid[pos] = (unsigned short)b;
    }
  }
  __syncthreads();
  // phase 5: burst copy-out (consecutive p -> mostly consecutive global addrs)
  int cc = E - base;
  if (cc > CHUNK) cc = CHUNK;
  for (int p = threadIdx.x; p < cc; p += 256) {
    int b = bid[p];
    stage[hist[b] + (p - lstart[b])] = vals[p];
  }
}

// ---------------- k5: bucket aggregate (LDS f32 atomics) + fused transform ----------------
__global__ __launch_bounds__(512) void kgat_aggr_fused(
    const int* __restrict__ boff, const int* __restrict__ stage,
    const float* __restrict__ emb, const float* __restrict__ hdot,
    const float* __restrict__ rb, const float* __restrict__ Ww,
    const float* __restrict__ Wb, float* __restrict__ out, int n) {
  __shared__ float acc[128][64];   // 32 KB
  __shared__ float scs[128][2];    // 1 KB
  __shared__ float Ws[64][68];     // 17.4 KB ; Ws[i][j] = Ww[j][i]
  int tid = threadIdx.x;
  int b = blockIdx.x;
  int h0 = b << BSH;
  for (int i = tid; i < 128 * 64; i += 512) ((float*)acc)[i] = 0.f;
  for (int idx = tid; idx < 64 * 64; idx += 512) {
    int j = idx >> 6, i = idx & 63;
    Ws[i][j] = Ww[idx];
  }
  float r0 = rb[0], r1 = rb[1];
  for (int i = tid; i < 128; i += 512) {
    int h = h0 + i;
    float hd = (h < n) ? hdot[h] : 0.f;
    scs[i][0] = 1.0f / (1.0f + __expf(-(hd + r0)));
    scs[i][1] = 1.0f / (1.0f + __expf(-(hd + r1)));
  }
  __syncthreads();
  int q = tid & 15;
  int grp = tid >> 4;  // 0..31
  int p0 = boff[b], p1 = boff[b + 1];
  const float4* emb4 = (const float4*)emb;
  for (int p = p0 + grp; p < p1; p += 32) {
    int v = stage[p];
    int hl = (v >> 19) & 127;
    float s = scs[hl][(v >> 18) & 1];
    float4 t = emb4[(v & TMASK) * 16 + q];
    float* a = &acc[hl][q * 4];
    atomicAdd(a + 0, s * t.x);
    atomicAdd(a + 1, s * t.y);
    atomicAdd(a + 2, s * t.z);
    atomicAdd(a + 3, s * t.w);
  }
  __syncthreads();
  // transform: 32 groups x 4 heads each; a comes from LDS acc
  float4 bb = ((const float4*)Wb)[q];
  int lanebase = (tid & 63) & ~15;
  for (int hh = grp; hh < 128; hh += 32) {
    int h = h0 + hh;
    if (h >= n) continue;
    float4 a = *(const float4*)&acc[hh][q * 4];
    float4 o = bb;
#pragma unroll 4
    for (int j = 0; j < 16; ++j) {
      float a0 = __shfl(a.x, lanebase + j);
      float a1 = __shfl(a.y, lanebase + j);
      float a2 = __shfl(a.z, lanebase + j);
      float a3 = __shfl(a.w, lanebase + j);
      float4 w0 = *(const float4*)&Ws[4 * j + 0][4 * q];
      float4 w1 = *(const float4*)&Ws[4 * j + 1][4 * q];
      float4 w2 = *(const float4*)&Ws[4 * j + 2][4 * q];
      float4 w3 = *(const float4*)&Ws[4 * j + 3][4 * q];
      o.x = fmaf(a0, w0.x, o.x); o.y = fmaf(a0, w0.y, o.y);
      o.z = fmaf(a0, w0.z, o.z); o.w = fmaf(a0, w0.w, o.w);
      o.x = fmaf(a1, w1.x, o.x); o.y = fmaf(a1, w1.y, o.y);
      o.z = fmaf(a1, w1.z, o.z); o.w = fmaf(a1, w1.w, o.w);
      o.x = fmaf(a2, w2.x, o.x); o.y = fmaf(a2, w2.y, o.y);
      o.z = fmaf(a2, w2.z, o.z); o.w = fmaf(a2, w2.w, o.w);
      o.x = fmaf(a3, w3.x, o.x); o.y = fmaf(a3, w3.y, o.y);
      o.z = fmaf(a3, w3.z, o.z); o.w = fmaf(a3, w3.w, o.w);
    }
    o.x = tanhf(o.x); o.y = tanhf(o.y); o.z = tanhf(o.z); o.w = tanhf(o.w);
    ((float4*)out)[h * 16 + q] = o;
  }
}

extern "C" void kernel_launch(void* const* d_in, const int* in_sizes, int n_in,
                              void* d_out, int out_size, void* d_ws, size_t ws_size,
                              hipStream_t stream) {
  const int* edge_index = (const int*)d_in[0];
  const int* edge_type  = (const int*)d_in[1];
  const float* entity_emb   = (const float*)d_in[2];
  const float* relation_emb = (const float*)d_in[3];
  const float* att_w = (const float*)d_in[4];
  const float* att_b = (const float*)d_in[5];
  const float* W_w   = (const float*)d_in[6];
  const float* W_b   = (const float*)d_in[7];
  float* out = (float*)d_out;

  const int E     = in_sizes[0] / 2;
  const int N_ENT = in_sizes[2] / DIM;
  const int N_REL = in_sizes[3] / DIM;
  const int NBK   = (N_ENT + 127) >> BSH;

  // ws layout (4B units)
  int* w32 = (int*)d_ws;
  float* hdot = (float*)w32;              // N_ENT
  float* rb   = (float*)(w32 + N_ENT);    // 8
  int*   bcnt = w32 + N_ENT + 8;          // NBK*16 (padded, 1/line)
  int*   boff = bcnt + NBK * 16;          // NBK+1
  int*   gcur = boff + NBK + 1;           // NBK*16 (padded, 1/line)
  int*   stage= gcur + NBK * 16;          // E

  hipMemsetAsync(bcnt, 0, (size_t)NBK * 16 * sizeof(int), stream);

  {
    int blocks = ((N_ENT + N_REL) * 16 + 255) / 256;
    kgat_hdot<<<blocks, 256, 0, stream>>>(entity_emb, relation_emb, att_w, att_b,
                                          hdot, rb, N_ENT, N_REL);
  }
  int eblocks = (E + CHUNK - 1) / CHUNK;
  kgat_bhist<<<eblocks, 256, 0, stream>>>(edge_index, bcnt, E, NBK);
  kgat_bscan<<<1, 256, 0, stream>>>(bcnt, boff, gcur, NBK);
  kgat_scatter1<<<eblocks, 256, 0, stream>>>(edge_index, edge_type, gcur, stage, E, NBK);
  kgat_aggr_fused<<<NBK, 512, 0, stream>>>(boff, stage, entity_emb, hdot, rb,
                                           W_w, W_b, out, N_ENT);
}

// Round 9
// 248.945 us; speedup vs baseline: 3.6156x; 3.6156x over previous
//
#include <hip/hip_runtime.h>
#include <hip/hip_bf16.h>

// KGAT via on-device CSR (no float atomics):
//   k1 hdot:  hdot[n] = emb[n].att_w[0:64];  rb[r] = rel[r].att_w[64:128] + b
//   k2 hist:  cnt[head]++                      (int atomics)
//   k3 scan:  off = exclusive_scan(cnt); boff/gcur at 256-head bucket bounds
//   k4 scatter1: per 6144-edge chunk: LDS hist(782) -> LDS scan -> LDS group
//              -> burst copy-out at atomically-reserved global ranges
//              (avg run ~8 entries = 32B granules -> ~2x write amp, was 16x)
//              packed 4B: (head&255)<<19 | rel<<18 | tail(18b)
//   k5 scatter2: block per bucket, 256 LDS cursors -> exact CSR slot
//              (writes land in a 10KB L2-hot window)
//   k6 aggr+xform fused (round-7 proven): per-head register segment-sum,
//              then tanh(acc @ W^T + b) via 16-lane shfl scheme, grid-stride.
// LESSON (round 8): do NOT aggregate via LDS f32 atomics - 128M serialized
// LDS RMWs cost ~700us. Register segsum is the right aggregation.

#define DIM 64
#define TMASK 0x3FFFF
#define RBIT (1 << 18)
#define BSH 8            // 256 heads per bucket
#define NBK_MAX 800      // >= ceil(200000/256) = 782
#define CHUNK 6144
#define SCAN_ITEMS 4     // 256*4 = 1024 >= NBK

// ---------------- k1: per-entity attention dot ----------------
__global__ __launch_bounds__(256) void kgat_hdot(
    const float* __restrict__ emb, const float* __restrict__ rel,
    const float* __restrict__ att_w, const float* __restrict__ att_b,
    float* __restrict__ hdot, float* __restrict__ rb,
    int n_ent, int n_rel) {
  int gid = blockIdx.x * 256 + threadIdx.x;
  int n = gid >> 4;
  int q = threadIdx.x & 15;
  if (n >= n_ent + n_rel) return;
  float4 v, w;
  if (n < n_ent) {
    v = ((const float4*)emb)[n * 16 + q];
    w = ((const float4*)att_w)[q];
  } else {
    v = ((const float4*)rel)[(n - n_ent) * 16 + q];
    w = ((const float4*)att_w)[16 + q];
  }
  float p = v.x * w.x + v.y * w.y + v.z * w.z + v.w * w.w;
  p += __shfl_xor(p, 1);
  p += __shfl_xor(p, 2);
  p += __shfl_xor(p, 4);
  p += __shfl_xor(p, 8);
  if (q == 0) {
    if (n < n_ent) hdot[n] = p;
    else rb[n - n_ent] = p + att_b[0];
  }
}

// ---------------- k2: histogram of head degrees ----------------
__global__ __launch_bounds__(256) void kgat_hist(
    const int* __restrict__ ei, int* __restrict__ cnt, int E) {
  int e = blockIdx.x * 256 + threadIdx.x;
  if (e < E) atomicAdd(&cnt[ei[e]], 1);
}

// ---------------- k3: exclusive scan (1024 elems / block) ----------------
__global__ __launch_bounds__(256) void scan_a(
    const int* __restrict__ cnt, int* __restrict__ incl,
    int* __restrict__ partial, int n) {
  __shared__ int s[256];
  int base = blockIdx.x * 1024 + threadIdx.x * 4;
  int v0 = 0, v1 = 0, v2 = 0, v3 = 0;
  if (base + 0 < n) v0 = cnt[base + 0];
  if (base + 1 < n) v1 = cnt[base + 1];
  if (base + 2 < n) v2 = cnt[base + 2];
  if (base + 3 < n) v3 = cnt[base + 3];
  int tsum = v0 + v1 + v2 + v3;
  s[threadIdx.x] = tsum;
  __syncthreads();
  for (int d = 1; d < 256; d <<= 1) {
    int val = (threadIdx.x >= (unsigned)d) ? s[threadIdx.x - d] : 0;
    __syncthreads();
    s[threadIdx.x] += val;
    __syncthreads();
  }
  int texcl = s[threadIdx.x] - tsum;
  if (base + 0 < n) incl[base + 0] = texcl + v0;
  if (base + 1 < n) incl[base + 1] = texcl + v0 + v1;
  if (base + 2 < n) incl[base + 2] = texcl + v0 + v1 + v2;
  if (base + 3 < n) incl[base + 3] = texcl + tsum;
  if (threadIdx.x == 255) partial[blockIdx.x] = s[255];
}

__global__ __launch_bounds__(256) void scan_b(int* __restrict__ partial, int nb) {
  __shared__ int s[256];
  int v = (threadIdx.x < (unsigned)nb) ? partial[threadIdx.x] : 0;
  s[threadIdx.x] = v;
  __syncthreads();
  for (int d = 1; d < 256; d <<= 1) {
    int val = (threadIdx.x >= (unsigned)d) ? s[threadIdx.x - d] : 0;
    __syncthreads();
    s[threadIdx.x] += val;
    __syncthreads();
  }
  if (threadIdx.x < (unsigned)nb) partial[threadIdx.x] = s[threadIdx.x] - v;
}

__global__ __launch_bounds__(256) void scan_c(
    const int* __restrict__ incl, const int* __restrict__ cnt,
    const int* __restrict__ partial, int* __restrict__ off,
    int* __restrict__ boff, int* __restrict__ gcur, int n) {
  int i = blockIdx.x * 256 + threadIdx.x;
  if (i >= n) return;
  int c = cnt[i];
  int o = incl[i] - c + partial[i >> 10];
  off[i] = o;
  if ((i & 255) == 0) {
    boff[i >> 8] = o;
    gcur[(i >> 8) << 4] = o;   // padded: 1 cursor per 64B line
  }
  if (i == n - 1) {
    off[n] = o + c;                 // = E
    boff[((n + 255) >> 8)] = o + c; // sentinel bucket end
  }
}

// ---------------- k4: binned scatter with coalesced burst writes ----------------
__global__ __launch_bounds__(256) void kgat_scatter1(
    const int* __restrict__ ei, const int* __restrict__ et,
    int* __restrict__ gcur, int* __restrict__ stage, int E, int nbk) {
  __shared__ int hist[NBK_MAX];    // counts, then global base
  __shared__ int lstart[NBK_MAX];
  __shared__ int lcur[NBK_MAX];
  __shared__ int sblk[256];
  __shared__ int vals[CHUNK];
  __shared__ unsigned short bid[CHUNK];
  int base = blockIdx.x * CHUNK;
  // phase 1: zero + local histogram
  for (int i = threadIdx.x; i < NBK_MAX; i += 256) hist[i] = 0;
  __syncthreads();
  for (int i = threadIdx.x; i < CHUNK; i += 256) {
    int e = base + i;
    if (e < E) atomicAdd(&hist[ei[e] >> BSH], 1);
  }
  __syncthreads();
  // phase 2: LDS scan -> lstart/lcur
  int v[SCAN_ITEMS];
  int s = 0;
#pragma unroll
  for (int k = 0; k < SCAN_ITEMS; ++k) {
    int idx = threadIdx.x * SCAN_ITEMS + k;
    v[k] = (idx < nbk) ? hist[idx] : 0;
    s += v[k];
  }
  sblk[threadIdx.x] = s;
  __syncthreads();
  for (int d = 1; d < 256; d <<= 1) {
    int t = (threadIdx.x >= (unsigned)d) ? sblk[threadIdx.x - d] : 0;
    __syncthreads();
    sblk[threadIdx.x] += t;
    __syncthreads();
  }
  int excl = sblk[threadIdx.x] - s;
#pragma unroll
  for (int k = 0; k < SCAN_ITEMS; ++k) {
    int idx = threadIdx.x * SCAN_ITEMS + k;
    if (idx < nbk) {
      lstart[idx] = excl;
      lcur[idx] = excl;
    }
    excl += v[k];
  }
  __syncthreads();
  // phase 3: reserve global ranges (counts still in hist) -> hist := gbase
  for (int b = threadIdx.x; b < nbk; b += 256) {
    int c = hist[b];
    hist[b] = c ? atomicAdd(&gcur[b << 4], c) : 0;
  }
  __syncthreads();
  // phase 4: re-read edges, group into LDS
  for (int i = threadIdx.x; i < CHUNK; i += 256) {
    int e = base + i;
    if (e < E) {
      int h = ei[e];
      int t = ei[E + e];
      int r = et[e];
      int b = h >> BSH;
      int pos = atomicAdd(&lcur[b], 1);
      vals[pos] = t | (r << 18) | ((h & 255) << 19);
      bid[pos] = (unsigned short)b;
    }
  }
  __syncthreads();
  // phase 5: burst copy-out (consecutive p -> consecutive global addrs per run)
  int cc = E - base;
  if (cc > CHUNK) cc = CHUNK;
  for (int p = threadIdx.x; p < cc; p += 256) {
    int b = bid[p];
    stage[hist[b] + (p - lstart[b])] = vals[p];
  }
}

// ---------------- k5: stage-2 in-bucket placement (block per bucket) ----------------
__global__ __launch_bounds__(256) void kgat_scatter2(
    const int* __restrict__ stage, const int* __restrict__ off,
    const int* __restrict__ boff, int* __restrict__ payload, int n) {
  __shared__ int lcur[256];
  int b = blockIdx.x;
  int s0 = boff[b], s1 = boff[b + 1];
  int hidx = (b << 8) + threadIdx.x;
  lcur[threadIdx.x] = off[hidx < n ? hidx : n];
  __syncthreads();
  for (int p = s0 + threadIdx.x; p < s1; p += 256) {
    int v = stage[p];
    int hl = (v >> 19) & 255;
    int pos = atomicAdd(&lcur[hl], 1);
    payload[pos] = v;
  }
}

// ---------------- k6: segment-sum + fused tanh(acc @ W^T + b) ----------------
__global__ __launch_bounds__(256) void kgat_aggr_fused(
    const int* __restrict__ off, const int* __restrict__ payload,
    const float* __restrict__ emb, const float* __restrict__ hdot,
    const float* __restrict__ rb, const float* __restrict__ Ww,
    const float* __restrict__ Wb, float* __restrict__ out, int n) {
  __shared__ float Ws[64][68];  // Ws[i][j] = Ww[j][i]
  for (int idx = threadIdx.x; idx < 64 * 64; idx += 256) {
    int j = idx >> 6, i = idx & 63;
    Ws[i][j] = Ww[idx];
  }
  __syncthreads();
  int q = threadIdx.x & 15;
  int grp = threadIdx.x >> 4;
  int lanebase = (threadIdx.x & 63) & ~15;
  int stride = gridDim.x * 16;
  float r0 = rb[0], r1 = rb[1];
  float4 bb = ((const float4*)Wb)[q];
  const float4* emb4 = (const float4*)emb;
  for (int h = blockIdx.x * 16 + grp; h < n; h += stride) {
    int p = off[h];
    int p1 = off[h + 1];
    float hd = hdot[h];
    float sc0 = 1.0f / (1.0f + __expf(-(hd + r0)));
    float sc1 = 1.0f / (1.0f + __expf(-(hd + r1)));
    float4 acc = make_float4(0.f, 0.f, 0.f, 0.f);
    for (; p + 4 <= p1; p += 4) {
      int v0 = payload[p + 0];
      int v1 = payload[p + 1];
      int v2 = payload[p + 2];
      int v3 = payload[p + 3];
      float4 t0 = emb4[(v0 & TMASK) * 16 + q];
      float4 t1 = emb4[(v1 & TMASK) * 16 + q];
      float4 t2 = emb4[(v2 & TMASK) * 16 + q];
      float4 t3 = emb4[(v3 & TMASK) * 16 + q];
      float s0 = (v0 & RBIT) ? sc1 : sc0;
      float s1 = (v1 & RBIT) ? sc1 : sc0;
      float s2 = (v2 & RBIT) ? sc1 : sc0;
      float s3 = (v3 & RBIT) ? sc1 : sc0;
      acc.x = fmaf(s0, t0.x, acc.x); acc.y = fmaf(s0, t0.y, acc.y);
      acc.z = fmaf(s0, t0.z, acc.z); acc.w = fmaf(s0, t0.w, acc.w);
      acc.x = fmaf(s1, t1.x, acc.x); acc.y = fmaf(s1, t1.y, acc.y);
      acc.z = fmaf(s1, t1.z, acc.z); acc.w = fmaf(s1, t1.w, acc.w);
      acc.x = fmaf(s2, t2.x, acc.x); acc.y = fmaf(s2, t2.y, acc.y);
      acc.z = fmaf(s2, t2.z, acc.z); acc.w = fmaf(s2, t2.w, acc.w);
      acc.x = fmaf(s3, t3.x, acc.x); acc.y = fmaf(s3, t3.y, acc.y);
      acc.z = fmaf(s3, t3.z, acc.z); acc.w = fmaf(s3, t3.w, acc.w);
    }
    for (; p < p1; ++p) {
      int v0 = payload[p];
      float s0 = (v0 & RBIT) ? sc1 : sc0;
      float4 t0 = emb4[(v0 & TMASK) * 16 + q];
      acc.x = fmaf(s0, t0.x, acc.x); acc.y = fmaf(s0, t0.y, acc.y);
      acc.z = fmaf(s0, t0.z, acc.z); acc.w = fmaf(s0, t0.w, acc.w);
    }
    // fused transform: o = tanh(W @ acc + b), acc distributed over 16 lanes
    float4 o = bb;
#pragma unroll 4
    for (int j = 0; j < 16; ++j) {
      float a0 = __shfl(acc.x, lanebase + j);
      float a1 = __shfl(acc.y, lanebase + j);
      float a2 = __shfl(acc.z, lanebase + j);
      float a3 = __shfl(acc.w, lanebase + j);
      float4 w0 = *(const float4*)&Ws[4 * j + 0][4 * q];
      float4 w1 = *(const float4*)&Ws[4 * j + 1][4 * q];
      float4 w2 = *(const float4*)&Ws[4 * j + 2][4 * q];
      float4 w3 = *(const float4*)&Ws[4 * j + 3][4 * q];
      o.x = fmaf(a0, w0.x, o.x); o.y = fmaf(a0, w0.y, o.y);
      o.z = fmaf(a0, w0.z, o.z); o.w = fmaf(a0, w0.w, o.w);
      o.x = fmaf(a1, w1.x, o.x); o.y = fmaf(a1, w1.y, o.y);
      o.z = fmaf(a1, w1.z, o.z); o.w = fmaf(a1, w1.w, o.w);
      o.x = fmaf(a2, w2.x, o.x); o.y = fmaf(a2, w2.y, o.y);
      o.z = fmaf(a2, w2.z, o.z); o.w = fmaf(a2, w2.w, o.w);
      o.x = fmaf(a3, w3.x, o.x); o.y = fmaf(a3, w3.y, o.y);
      o.z = fmaf(a3, w3.z, o.z); o.w = fmaf(a3, w3.w, o.w);
    }
    o.x = tanhf(o.x); o.y = tanhf(o.y); o.z = tanhf(o.z); o.w = tanhf(o.w);
    ((float4*)out)[h * 16 + q] = o;
  }
}

extern "C" void kernel_launch(void* const* d_in, const int* in_sizes, int n_in,
                              void* d_out, int out_size, void* d_ws, size_t ws_size,
                              hipStream_t stream) {
  const int* edge_index = (const int*)d_in[0];
  const int* edge_type  = (const int*)d_in[1];
  const float* entity_emb   = (const float*)d_in[2];
  const float* relation_emb = (const float*)d_in[3];
  const float* att_w = (const float*)d_in[4];
  const float* att_b = (const float*)d_in[5];
  const float* W_w   = (const float*)d_in[6];
  const float* W_b   = (const float*)d_in[7];
  float* out = (float*)d_out;

  const int E     = in_sizes[0] / 2;
  const int N_ENT = in_sizes[2] / DIM;
  const int N_REL = in_sizes[3] / DIM;
  const int NBK   = (N_ENT + 255) >> BSH;

  // ws layout (4B units)
  int* w32 = (int*)d_ws;
  float* hdot   = (float*)w32;                 // N_ENT
  float* rb     = (float*)(w32 + N_ENT);       // 8
  int*   cnt    = w32 + N_ENT + 8;             // N_ENT
  int*   off    = cnt + N_ENT;                 // N_ENT + 1
  int*   boff   = off + N_ENT + 1;             // NBK + 1
  int*   gcur   = boff + NBK + 1;              // NBK * 16 (padded, 1/line)
  int*   partial= gcur + NBK * 16;             // 256
  int*   stage  = partial + 256;               // E
  int*   payload= stage + E;                   // E

  hipMemsetAsync(cnt, 0, (size_t)N_ENT * sizeof(int), stream);

  {
    int blocks = ((N_ENT + N_REL) * 16 + 255) / 256;
    kgat_hdot<<<blocks, 256, 0, stream>>>(entity_emb, relation_emb, att_w, att_b,
                                          hdot, rb, N_ENT, N_REL);
  }
  kgat_hist<<<(E + 255) / 256, 256, 0, stream>>>(edge_index, cnt, E);
  {
    int nb = (N_ENT + 1023) / 1024;
    scan_a<<<nb, 256, 0, stream>>>(cnt, off, partial, N_ENT);
    scan_b<<<1, 256, 0, stream>>>(partial, nb);
    scan_c<<<(N_ENT + 255) / 256, 256, 0, stream>>>(off, cnt, partial, off, boff, gcur, N_ENT);
  }
  {
    int eblocks = (E + CHUNK - 1) / CHUNK;
    kgat_scatter1<<<eblocks, 256, 0, stream>>>(edge_index, edge_type, gcur, stage, E, NBK);
  }
  kgat_scatter2<<<NBK, 256, 0, stream>>>(stage, off, boff, payload, N_ENT);
  kgat_aggr_fused<<<2048, 256, 0, stream>>>(off, payload, entity_emb, hdot, rb,
                                            W_w, W_b, out, N_ENT);
}

// Round 11
// 186.866 us; speedup vs baseline: 4.8168x; 1.3322x over previous
//
#include <hip/hip_runtime.h>
#include <hip/hip_bf16.h>

// KGAT via on-device CSR (no float atomics):
//   k1 hdot:   hdot[n] = emb[n].att_w[0:64]; rb[r] = rel[r].att_w[64:128] + b
//   k2 bhist:  per-block LDS histogram of head>>8 -> padded bcnt (batched flush)
//   k3 bscan:  1-block scan of 782 bucket counts -> boff, gcur
//   k4 scatter1: per 6144-edge chunk: LDS hist -> LDS scan -> LDS group ->
//              burst copy-out at atomically-reserved ranges (runs ~8 -> low amp)
//              packed 4B: (head&255)<<19 | rel<<18 | tail(18b)
//   k5 scatter2: block per bucket; LDS counting sort over 256 head-lows;
//              writes per-head off[] itself (replaces global hist+scan) and
//              places payload at exact CSR slots (10KB L2-hot window)
//   k6 aggr+xform fused: per-head register segment-sum (f32 gathers),
//              then tanh(acc @ W^T + b) via 16-lane shfl scheme, grid-stride.
// LESSONS: (r8) never aggregate via LDS f32 atomics (~700us). (r6/r7) pad
// global atomic counters 1/cache-line. (r4/r5) amortize LDS W-staging via
// grid-stride; cap unroll to keep VGPR<=96. (r10) bf16 compression of the
// gathered tail rows FAILS absmax (0.023 > 0.02) - gathers must stay f32.

#define DIM 64
#define TMASK 0x3FFFF
#define RBIT (1 << 18)
#define BSH 8            // 256 heads per bucket
#define NBK_MAX 800      // >= ceil(200000/256) = 782
#define CHUNK 6144
#define SCAN_ITEMS 4     // 256*4 = 1024 >= NBK

// ---------------- k1: per-entity attention dot ----------------
__global__ __launch_bounds__(256) void kgat_hdot(
    const float* __restrict__ emb, const float* __restrict__ rel,
    const float* __restrict__ att_w, const float* __restrict__ att_b,
    float* __restrict__ hdot, float* __restrict__ rb,
    int n_ent, int n_rel) {
  int gid = blockIdx.x * 256 + threadIdx.x;
  int n = gid >> 4;
  int q = threadIdx.x & 15;
  if (n >= n_ent + n_rel) return;
  float4 v, w;
  if (n < n_ent) {
    v = ((const float4*)emb)[n * 16 + q];
    w = ((const float4*)att_w)[q];
  } else {
    v = ((const float4*)rel)[(n - n_ent) * 16 + q];
    w = ((const float4*)att_w)[16 + q];
  }
  float p = v.x * w.x + v.y * w.y + v.z * w.z + v.w * w.w;
  p += __shfl_xor(p, 1);
  p += __shfl_xor(p, 2);
  p += __shfl_xor(p, 4);
  p += __shfl_xor(p, 8);
  if (q == 0) {
    if (n < n_ent) hdot[n] = p;
    else rb[n - n_ent] = p + att_b[0];
  }
}

// ---------------- k2: bucket histogram (LDS, batched flush) ----------------
__global__ __launch_bounds__(256) void kgat_bhist(
    const int* __restrict__ ei, int* __restrict__ bcnt, int E, int nbk) {
  __shared__ int hist[NBK_MAX];
  for (int i = threadIdx.x; i < NBK_MAX; i += 256) hist[i] = 0;
  __syncthreads();
  int base = blockIdx.x * CHUNK;
  for (int i = threadIdx.x; i < CHUNK; i += 256) {
    int e = base + i;
    if (e < E) atomicAdd(&hist[ei[e] >> BSH], 1);
  }
  __syncthreads();
  for (int b = threadIdx.x; b < nbk; b += 256) {
    int c = hist[b];
    if (c) atomicAdd(&bcnt[b << 4], c);  // padded: 1 counter / 64B line
  }
}

// ---------------- k3: 1-block scan of bucket counts ----------------
__global__ __launch_bounds__(256) void kgat_bscan(
    const int* __restrict__ bcnt, int* __restrict__ boff,
    int* __restrict__ gcur, int nbk) {
  __shared__ int sblk[256];
  int v[SCAN_ITEMS];
  int s = 0;
#pragma unroll
  for (int k = 0; k < SCAN_ITEMS; ++k) {
    int idx = threadIdx.x * SCAN_ITEMS + k;
    v[k] = (idx < nbk) ? bcnt[idx << 4] : 0;
    s += v[k];
  }
  sblk[threadIdx.x] = s;
  __syncthreads();
  for (int d = 1; d < 256; d <<= 1) {
    int t = (threadIdx.x >= (unsigned)d) ? sblk[threadIdx.x - d] : 0;
    __syncthreads();
    sblk[threadIdx.x] += t;
    __syncthreads();
  }
  int excl = sblk[threadIdx.x] - s;
#pragma unroll
  for (int k = 0; k < SCAN_ITEMS; ++k) {
    int idx = threadIdx.x * SCAN_ITEMS + k;
    if (idx < nbk) {
      boff[idx] = excl;
      gcur[idx << 4] = excl;
    }
    excl += v[k];
  }
  if (threadIdx.x == 255) boff[nbk] = excl;  // = E
}

// ---------------- k4: binned scatter with coalesced burst writes ----------------
__global__ __launch_bounds__(256) void kgat_scatter1(
    const int* __restrict__ ei, const int* __restrict__ et,
    int* __restrict__ gcur, int* __restrict__ stage, int E, int nbk) {
  __shared__ int hist[NBK_MAX];    // counts, then global base
  __shared__ int lstart[NBK_MAX];
  __shared__ int lcur[NBK_MAX];
  __shared__ int sblk[256];
  __shared__ int vals[CHUNK];
  __shared__ unsigned short bid[CHUNK];
  int base = blockIdx.x * CHUNK;
  for (int i = threadIdx.x; i < NBK_MAX; i += 256) hist[i] = 0;
  __syncthreads();
  for (int i = threadIdx.x; i < CHUNK; i += 256) {
    int e = base + i;
    if (e < E) atomicAdd(&hist[ei[e] >> BSH], 1);
  }
  __syncthreads();
  int v[SCAN_ITEMS];
  int s = 0;
#pragma unroll
  for (int k = 0; k < SCAN_ITEMS; ++k) {
    int idx = threadIdx.x * SCAN_ITEMS + k;
    v[k] = (idx < nbk) ? hist[idx] : 0;
    s += v[k];
  }
  sblk[threadIdx.x] = s;
  __syncthreads();
  for (int d = 1; d < 256; d <<= 1) {
    int t = (threadIdx.x >= (unsigned)d) ? sblk[threadIdx.x - d] : 0;
    __syncthreads();
    sblk[threadIdx.x] += t;
    __syncthreads();
  }
  int excl = sblk[threadIdx.x] - s;
#pragma unroll
  for (int k = 0; k < SCAN_ITEMS; ++k) {
    int idx = threadIdx.x * SCAN_ITEMS + k;
    if (idx < nbk) {
      lstart[idx] = excl;
      lcur[idx] = excl;
    }
    excl += v[k];
  }
  __syncthreads();
  for (int b = threadIdx.x; b < nbk; b += 256) {
    int c = hist[b];
    hist[b] = c ? atomicAdd(&gcur[b << 4], c) : 0;
  }
  __syncthreads();
  for (int i = threadIdx.x; i < CHUNK; i += 256) {
    int e = base + i;
    if (e < E) {
      int h = ei[e];
      int t = ei[E + e];
      int r = et[e];
      int b = h >> BSH;
      int pos = atomicAdd(&lcur[b], 1);
      vals[pos] = t | (r << 18) | ((h & 255) << 19);
      bid[pos] = (unsigned short)b;
    }
  }
  __syncthreads();
  int cc = E - base;
  if (cc > CHUNK) cc = CHUNK;
  for (int p = threadIdx.x; p < cc; p += 256) {
    int b = bid[p];
    stage[hist[b] + (p - lstart[b])] = vals[p];
  }
}

// ---------------- k5: in-bucket counting sort; writes off[] + payload ----------------
__global__ __launch_bounds__(256) void kgat_scatter2(
    const int* __restrict__ stage, const int* __restrict__ boff,
    int* __restrict__ off, int* __restrict__ payload) {
  __shared__ int hist[256];
  __shared__ int sc[256];
  __shared__ int lcur[256];
  int b = blockIdx.x;
  int tid = threadIdx.x;
  int s0 = boff[b], s1 = boff[b + 1];
  hist[tid] = 0;
  __syncthreads();
  for (int p = s0 + tid; p < s1; p += 256)
    atomicAdd(&hist[(stage[p] >> 19) & 255], 1);
  __syncthreads();
  int c = hist[tid];
  sc[tid] = c;
  __syncthreads();
  for (int d = 1; d < 256; d <<= 1) {
    int t = (tid >= d) ? sc[tid - d] : 0;
    __syncthreads();
    sc[tid] += t;
    __syncthreads();
  }
  int basep = s0 + sc[tid] - c;   // exclusive start for head (b<<8)+tid
  off[(b << 8) + tid] = basep;    // heads past n get basep = s1 (hist=0)
  lcur[tid] = basep;
  __syncthreads();
  for (int p = s0 + tid; p < s1; p += 256) {
    int vv = stage[p];
    int pos = atomicAdd(&lcur[(vv >> 19) & 255], 1);
    payload[pos] = vv;
  }
}

// ---------------- k6: segment-sum + fused tanh(acc @ W^T + b) ----------------
__global__ __launch_bounds__(256) void kgat_aggr_fused(
    const int* __restrict__ off, const int* __restrict__ payload,
    const float* __restrict__ emb, const float* __restrict__ hdot,
    const float* __restrict__ rb, const float* __restrict__ Ww,
    const float* __restrict__ Wb, float* __restrict__ out, int n) {
  __shared__ float Ws[64][68];  // Ws[i][j] = Ww[j][i]
  for (int idx = threadIdx.x; idx < 64 * 64; idx += 256) {
    int j = idx >> 6, i = idx & 63;
    Ws[i][j] = Ww[idx];
  }
  __syncthreads();
  int q = threadIdx.x & 15;
  int grp = threadIdx.x >> 4;
  int lanebase = (threadIdx.x & 63) & ~15;
  int stride = gridDim.x * 16;
  float r0 = rb[0], r1 = rb[1];
  float4 bb = ((const float4*)Wb)[q];
  const float4* emb4 = (const float4*)emb;
  for (int h = blockIdx.x * 16 + grp; h < n; h += stride) {
    int p = off[h];
    int p1 = off[h + 1];
    float hd = hdot[h];
    float sc0 = 1.0f / (1.0f + __expf(-(hd + r0)));
    float sc1 = 1.0f / (1.0f + __expf(-(hd + r1)));
    float4 acc = make_float4(0.f, 0.f, 0.f, 0.f);
    for (; p + 4 <= p1; p += 4) {
      int v0 = payload[p + 0];
      int v1 = payload[p + 1];
      int v2 = payload[p + 2];
      int v3 = payload[p + 3];
      float4 t0 = emb4[(v0 & TMASK) * 16 + q];
      float4 t1 = emb4[(v1 & TMASK) * 16 + q];
      float4 t2 = emb4[(v2 & TMASK) * 16 + q];
      float4 t3 = emb4[(v3 & TMASK) * 16 + q];
      float s0 = (v0 & RBIT) ? sc1 : sc0;
      float s1 = (v1 & RBIT) ? sc1 : sc0;
      float s2 = (v2 & RBIT) ? sc1 : sc0;
      float s3 = (v3 & RBIT) ? sc1 : sc0;
      acc.x = fmaf(s0, t0.x, acc.x); acc.y = fmaf(s0, t0.y, acc.y);
      acc.z = fmaf(s0, t0.z, acc.z); acc.w = fmaf(s0, t0.w, acc.w);
      acc.x = fmaf(s1, t1.x, acc.x); acc.y = fmaf(s1, t1.y, acc.y);
      acc.z = fmaf(s1, t1.z, acc.z); acc.w = fmaf(s1, t1.w, acc.w);
      acc.x = fmaf(s2, t2.x, acc.x); acc.y = fmaf(s2, t2.y, acc.y);
      acc.z = fmaf(s2, t2.z, acc.z); acc.w = fmaf(s2, t2.w, acc.w);
      acc.x = fmaf(s3, t3.x, acc.x); acc.y = fmaf(s3, t3.y, acc.y);
      acc.z = fmaf(s3, t3.z, acc.z); acc.w = fmaf(s3, t3.w, acc.w);
    }
    for (; p < p1; ++p) {
      int v0 = payload[p];
      float s0 = (v0 & RBIT) ? sc1 : sc0;
      float4 t0 = emb4[(v0 & TMASK) * 16 + q];
      acc.x = fmaf(s0, t0.x, acc.x); acc.y = fmaf(s0, t0.y, acc.y);
      acc.z = fmaf(s0, t0.z, acc.z); acc.w = fmaf(s0, t0.w, acc.w);
    }
    // fused transform: o = tanh(W @ acc + b), acc distributed over 16 lanes
    float4 o = bb;
#pragma unroll 4
    for (int j = 0; j < 16; ++j) {
      float a0 = __shfl(acc.x, lanebase + j);
      float a1 = __shfl(acc.y, lanebase + j);
      float a2 = __shfl(acc.z, lanebase + j);
      float a3 = __shfl(acc.w, lanebase + j);
      float4 w0 = *(const float4*)&Ws[4 * j + 0][4 * q];
      float4 w1 = *(const float4*)&Ws[4 * j + 1][4 * q];
      float4 w2 = *(const float4*)&Ws[4 * j + 2][4 * q];
      float4 w3 = *(const float4*)&Ws[4 * j + 3][4 * q];
      o.x = fmaf(a0, w0.x, o.x); o.y = fmaf(a0, w0.y, o.y);
      o.z = fmaf(a0, w0.z, o.z); o.w = fmaf(a0, w0.w, o.w);
      o.x = fmaf(a1, w1.x, o.x); o.y = fmaf(a1, w1.y, o.y);
      o.z = fmaf(a1, w1.z, o.z); o.w = fmaf(a1, w1.w, o.w);
      o.x = fmaf(a2, w2.x, o.x); o.y = fmaf(a2, w2.y, o.y);
      o.z = fmaf(a2, w2.z, o.z); o.w = fmaf(a2, w2.w, o.w);
      o.x = fmaf(a3, w3.x, o.x); o.y = fmaf(a3, w3.y, o.y);
      o.z = fmaf(a3, w3.z, o.z); o.w = fmaf(a3, w3.w, o.w);
    }
    o.x = tanhf(o.x); o.y = tanhf(o.y); o.z = tanhf(o.z); o.w = tanhf(o.w);
    ((float4*)out)[h * 16 + q] = o;
  }
}

extern "C" void kernel_launch(void* const* d_in, const int* in_sizes, int n_in,
                              void* d_out, int out_size, void* d_ws, size_t ws_size,
                              hipStream_t stream) {
  const int* edge_index = (const int*)d_in[0];
  const int* edge_type  = (const int*)d_in[1];
  const float* entity_emb   = (const float*)d_in[2];
  const float* relation_emb = (const float*)d_in[3];
  const float* att_w = (const float*)d_in[4];
  const float* att_b = (const float*)d_in[5];
  const float* W_w   = (const float*)d_in[6];
  const float* W_b   = (const float*)d_in[7];
  float* out = (float*)d_out;

  const int E     = in_sizes[0] / 2;
  const int N_ENT = in_sizes[2] / DIM;
  const int N_REL = in_sizes[3] / DIM;
  const int NBK   = (N_ENT + 255) >> BSH;

  // ws layout (4B units)
  int* w32 = (int*)d_ws;
  float* hdot = (float*)w32;                    // N_ENT
  float* rb   = (float*)(w32 + N_ENT);          // 8
  int*   bcnt = w32 + N_ENT + 8;                // NBK*16 (padded, 1/line)
  int*   boff = bcnt + NBK * 16;                // NBK+1
  int*   gcur = boff + NBK + 1;                 // NBK*16 (padded, 1/line)
  int*   off  = gcur + NBK * 16;                // NBK*256 + 1
  int*   stage   = off + NBK * 256 + 1;         // E
  int*   payload = stage + E;                   // E

  hipMemsetAsync(bcnt, 0, (size_t)NBK * 16 * sizeof(int), stream);

  {
    int blocks = ((N_ENT + N_REL) * 16 + 255) / 256;
    kgat_hdot<<<blocks, 256, 0, stream>>>(entity_emb, relation_emb, att_w, att_b,
                                          hdot, rb, N_ENT, N_REL);
  }
  int eblocks = (E + CHUNK - 1) / CHUNK;
  kgat_bhist<<<eblocks, 256, 0, stream>>>(edge_index, bcnt, E, NBK);
  kgat_bscan<<<1, 256, 0, stream>>>(bcnt, boff, gcur, NBK);
  kgat_scatter1<<<eblocks, 256, 0, stream>>>(edge_index, edge_type, gcur, stage, E, NBK);
  kgat_scatter2<<<NBK, 256, 0, stream>>>(stage, boff, off, payload);
  kgat_aggr_fused<<<2048, 256, 0, stream>>>(off, payload, entity_emb, hdot, rb,
                                            W_w, W_b, out, N_ENT);
}